// Round 1
// baseline (15135.979 us; speedup 1.0000x reference)
//
#include <hip/hip_runtime.h>
#include <math.h>

#define PI_F 3.14159265358979323846f

// ---------------------------------------------------------------------------
// 256-point Stockham radix-2 FFT in LDS. 256 threads, one output per thread
// per stage, auto-sorting (no bit reversal). Result ends in (sAr, sAi).
// Forward: e^{-2pi i}, Inverse: conj twiddles, NO scaling either way.
// ---------------------------------------------------------------------------
template<bool INVERSE>
__device__ __forceinline__ void fft256(float* sAr, float* sAi, float* sBr, float* sBi,
                                       const float* twr, const float* twi, int t)
{
  float *sr = sAr, *si = sAi, *dr = sBr, *di = sBi;
#pragma unroll
  for (int s = 0; s < 8; ++s) {
    __syncthreads();
    int m  = 1 << s;
    int k  = t & (m - 1);
    int jm = (t >> (s + 1)) << s;   // j*m  (also the twiddle index j<<s)
    int i0 = k + jm;
    float c0r = sr[i0],       c0i = si[i0];
    float c1r = sr[i0 + 128], c1i = si[i0 + 128];
    float orr, oii;
    if ((t >> s) & 1) {
      float xr = c0r - c1r, xi = c0i - c1i;
      float wr = twr[jm];
      float wi = INVERSE ? -twi[jm] : twi[jm];
      orr = xr * wr - xi * wi;
      oii = xr * wi + xi * wr;
    } else {
      orr = c0r + c1r;
      oii = c0i + c1i;
    }
    dr[t] = orr; di[t] = oii;
    float* tp;
    tp = sr; sr = dr; dr = tp;
    tp = si; si = di; di = tp;
  }
  __syncthreads();
}

#define DECL_FFT_LDS \
  __shared__ float sAr[256], sAi[256], sBr[256], sBi[256]; \
  __shared__ float twr[128], twi[128];

#define BUILD_TW(t) \
  do { if ((t) < 128) { float s_, c_; \
       __sincosf(-(2.0f * PI_F / 256.0f) * (float)(t), &s_, &c_); \
       twr[(t)] = c_; twi[(t)] = s_; } } while (0)

// ---------------------------------------------------------------------------
// Layouts (float2 unless noted):
//   u, h : [b][ky][kx]        8*129*256
//   G    : [f][b][ky][x]      4*8*129*256   (f: 0=vx 1=vy 2=gx 3=gy)
//   NL1  : [b][ky][x]         8*86*256      (ky 0..85 only; rfft_y of nl)
//   rec  : [r][b][ky][kx]     3*8*129*256
//   out  : [r][b][x][y] float 3*8*256*256
// ---------------------------------------------------------------------------

// --- initial: rfft along y for each (b, x) row ------------------------------
__global__ __launch_bounds__(256) void k_init_rows(const float* __restrict__ vort,
                                                   float2* __restrict__ W1)
{
  const int t = threadIdx.x, x = blockIdx.x, b = blockIdx.y;
  DECL_FFT_LDS
  BUILD_TW(t);
  sAr[t] = vort[((size_t)b * 256 + x) * 256 + t];
  sAi[t] = 0.0f;
  fft256<false>(sAr, sAi, sBr, sBi, twr, twi, t);
  if (t < 129) W1[((size_t)b * 129 + t) * 256 + x] = make_float2(sAr[t], sAi[t]);
}

// --- initial: complex FFT along x for each (b, ky) --------------------------
__global__ __launch_bounds__(256) void k_init_cols(const float2* __restrict__ W1,
                                                   float2* __restrict__ u)
{
  const int t = threadIdx.x, ky = blockIdx.x, b = blockIdx.y;
  DECL_FFT_LDS
  BUILD_TW(t);
  float2 v = W1[((size_t)b * 129 + ky) * 256 + t];
  sAr[t] = v.x; sAi[t] = v.y;
  fft256<false>(sAr, sAi, sBr, sBi, twr, twi, t);
  u[((size_t)b * 129 + ky) * 256 + t] = make_float2(sAr[t], sAi[t]);
}

// --- per-stage spectral kernel ----------------------------------------------
// fwd col FFT of NL1 -> adv_hat, filter, +f_hat, RK update of (u,h),
// optional record, then build 4 derivative fields of updated u and
// inverse col FFT each -> G.
__global__ __launch_bounds__(256) void k_spectral(
    const float2* __restrict__ NL1, float2* __restrict__ u, float2* __restrict__ h,
    float2* __restrict__ G, float2* __restrict__ rec,
    float beta, float gdt, float mu, int doUpdate, int recIdx)
{
  const int t = threadIdx.x, ky = blockIdx.x, b = blockIdx.y;
  DECL_FFT_LDS
  BUILD_TW(t);
  const size_t row = ((size_t)b * 129 + ky) * 256;
  float2 uu = u[row + t];
  float ur = uu.x, ui = uu.y;
  const int jx = (t < 128) ? t : t - 256;
  const float k2 = (float)(jx * jx + ky * ky);

  if (doUpdate) {
    float advr = 0.0f, advi = 0.0f;
    if (ky <= 85) {                                  // dealias filter in ky
      float2 nv = NL1[((size_t)b * 86 + ky) * 256 + t];
      sAr[t] = nv.x; sAi[t] = nv.y;
      fft256<false>(sAr, sAi, sBr, sBi, twr, twi, t);
      if (t < 85 || t >= 171) { advr = sAr[t]; advi = sAi[t]; }   // filter kx
    }
    if (t == 0 && ky == 4) {                         // forcing f_hat
      float s_, c_;
      __sincosf(PI_F / 64.0f, &s_, &c_);
      advr -= 131072.0f * c_;
      advi -= 131072.0f * s_;
    }
    float hr = advr, hi = advi;
    if (beta != 0.0f) {                              // beta==0 at stage 0: never read stale h
      float2 hh = h[row + t];
      hr += beta * hh.x; hi += beta * hh.y;
    }
    const float lin   = -0.001f * k2 - 0.1f;         // VISC*lap - DRAG
    const float anum  = 1.0f + mu * lin;
    const float invd  = 1.0f / (1.0f - mu * lin);
    ur = (ur * anum + gdt * hr) * invd;
    ui = (ui * anum + gdt * hi) * invd;
    u[row + t] = make_float2(ur, ui);
    h[row + t] = make_float2(hr, hi);
    if (recIdx >= 0)
      rec[((size_t)recIdx * 8 + b) * (129 * 256) + (size_t)ky * 256 + t] = make_float2(ur, ui);
  }

  // fields of updated u, with full irfft2 normalization 1/N^2 folded in
  const float NRM = 1.0f / 65536.0f;
  const float inv_lapnz = (k2 == 0.0f) ? 1.0f : (-1.0f / k2);
  const float urN = ur * NRM, uiN = ui * NRM;
  const float psr = -urN * inv_lapnz, psi_ = -uiN * inv_lapnz;   // psi = -u/lap_nz
  const float fjx = (float)jx, fjy = (float)ky;

  // f=0: vx_hat = i*jy*psi
  sAr[t] = -fjy * psi_; sAi[t] = fjy * psr;
  fft256<true>(sAr, sAi, sBr, sBi, twr, twi, t);
  G[(((size_t)0 * 8 + b) * 129 + ky) * 256 + t] = make_float2(sAr[t], sAi[t]);
  // f=1: vy_hat = -i*jx*psi
  sAr[t] = fjx * psi_; sAi[t] = -fjx * psr;
  fft256<true>(sAr, sAi, sBr, sBi, twr, twi, t);
  G[(((size_t)1 * 8 + b) * 129 + ky) * 256 + t] = make_float2(sAr[t], sAi[t]);
  // f=2: gx_hat = i*jx*u
  sAr[t] = -fjx * uiN; sAi[t] = fjx * urN;
  fft256<true>(sAr, sAi, sBr, sBi, twr, twi, t);
  G[(((size_t)2 * 8 + b) * 129 + ky) * 256 + t] = make_float2(sAr[t], sAi[t]);
  // f=3: gy_hat = i*jy*u
  sAr[t] = -fjy * uiN; sAi[t] = fjy * urN;
  fft256<true>(sAr, sAi, sBr, sBi, twr, twi, t);
  G[(((size_t)3 * 8 + b) * 129 + ky) * 256 + t] = make_float2(sAr[t], sAi[t]);
}

// --- per-stage real-space kernel: 4 x-rows per WG ---------------------------
// hermitian-paired inverse FFTs (vx+i*vy, gx+i*gy), nl = -(vx*gx+vy*gy),
// paired forward FFT of two real rows, write NL1 (ky<=85 only).
__global__ __launch_bounds__(256) void k_real(const float2* __restrict__ G,
                                              float2* __restrict__ NL1)
{
  const int t = threadIdx.x, xq = blockIdx.x, b = blockIdx.y;
  const int x0 = xq * 4;
  DECL_FFT_LDS
  __shared__ float t0r[644], t0i[644], t1r[644], t1i[644];   // [129][4] pad stride 5
  BUILD_TW(t);

  // tiles of fields 0 (vx) and 1 (vy)
  for (int i = t; i < 516; i += 256) {
    int ky = i >> 2, xl = i & 3;
    float2 a = G[(((size_t)0 * 8 + b) * 129 + ky) * 256 + x0 + xl];
    float2 c = G[(((size_t)1 * 8 + b) * 129 + ky) * 256 + x0 + xl];
    t0r[ky * 5 + xl] = a.x; t0i[ky * 5 + xl] = a.y;
    t1r[ky * 5 + xl] = c.x; t1i[ky * 5 + xl] = c.y;
  }
  __syncthreads();
  const int  kk    = (t <= 128) ? t : 256 - t;
  const bool lower = (t <= 128);
  float vxr[4], vyr[4];
#pragma unroll
  for (int xl = 0; xl < 4; ++xl) {
    float ar = t0r[kk * 5 + xl], ai = t0i[kk * 5 + xl];
    float br = t1r[kk * 5 + xl], bi = t1i[kk * 5 + xl];
    sAr[t] = lower ? (ar - bi) : (ar + bi);   // Z = Hvx + i*Hvy (hermitian ext)
    sAi[t] = lower ? (ai + br) : (br - ai);
    fft256<true>(sAr, sAi, sBr, sBi, twr, twi, t);
    vxr[xl] = sAr[t]; vyr[xl] = sAi[t];
  }
  __syncthreads();
  // tiles of fields 2 (gx) and 3 (gy)
  for (int i = t; i < 516; i += 256) {
    int ky = i >> 2, xl = i & 3;
    float2 a = G[(((size_t)2 * 8 + b) * 129 + ky) * 256 + x0 + xl];
    float2 c = G[(((size_t)3 * 8 + b) * 129 + ky) * 256 + x0 + xl];
    t0r[ky * 5 + xl] = a.x; t0i[ky * 5 + xl] = a.y;
    t1r[ky * 5 + xl] = c.x; t1i[ky * 5 + xl] = c.y;
  }
  __syncthreads();
  float nl[4];
#pragma unroll
  for (int xl = 0; xl < 4; ++xl) {
    float ar = t0r[kk * 5 + xl], ai = t0i[kk * 5 + xl];
    float br = t1r[kk * 5 + xl], bi = t1i[kk * 5 + xl];
    sAr[t] = lower ? (ar - bi) : (ar + bi);
    sAi[t] = lower ? (ai + br) : (br - ai);
    fft256<true>(sAr, sAi, sBr, sBi, twr, twi, t);
    float gx = sAr[t], gy = sAi[t];
    nl[xl] = -(vxr[xl] * gx + vyr[xl] * gy);
  }
  // paired forward rfft of (nl[0],nl[1]) and (nl[2],nl[3])
#pragma unroll
  for (int p = 0; p < 2; ++p) {
    sAr[t] = nl[2 * p]; sAi[t] = nl[2 * p + 1];
    fft256<false>(sAr, sAi, sBr, sBi, twr, twi, t);
    if (t <= 85) {
      int mI = (256 - t) & 255;
      float zr = sAr[t],  zi = sAi[t];
      float wr = sAr[mI], wi = sAi[mI];
      float f0r = 0.5f * (zr + wr), f0i = 0.5f * (zi - wi);
      float f1r = 0.5f * (zi + wi), f1i = 0.5f * (wr - zr);
      NL1[((size_t)b * 86 + t) * 256 + x0 + 2 * p]     = make_float2(f0r, f0i);
      NL1[((size_t)b * 86 + t) * 256 + x0 + 2 * p + 1] = make_float2(f1r, f1i);
    }
    __syncthreads();   // protect cross-lane reads of sA before next pair
  }
}

// --- final output: inverse col FFT of records -------------------------------
__global__ __launch_bounds__(256) void k_final_col(const float2* __restrict__ rec,
                                                   float2* __restrict__ G)
{
  const int t = threadIdx.x, ky = blockIdx.x, b = blockIdx.y, r = blockIdx.z;
  DECL_FFT_LDS
  BUILD_TW(t);
  const size_t row = (((size_t)r * 8 + b) * 129 + ky) * 256;
  float2 v = rec[row + t];
  sAr[t] = v.x; sAi[t] = v.y;
  fft256<true>(sAr, sAi, sBr, sBi, twr, twi, t);
  G[row + t] = make_float2(sAr[t], sAi[t]);
}

// --- final output: paired hermitian inverse row FFT -> real output ----------
__global__ __launch_bounds__(256) void k_final_row(const float2* __restrict__ G,
                                                   float* __restrict__ out)
{
  const int t = threadIdx.x, xq = blockIdx.x, b = blockIdx.y, r = blockIdx.z;
  const int x0 = xq * 4;
  DECL_FFT_LDS
  __shared__ float t0r[644], t0i[644];
  BUILD_TW(t);
  for (int i = t; i < 516; i += 256) {
    int ky = i >> 2, xl = i & 3;
    float2 a = G[(((size_t)r * 8 + b) * 129 + ky) * 256 + x0 + xl];
    t0r[ky * 5 + xl] = a.x; t0i[ky * 5 + xl] = a.y;
  }
  __syncthreads();
  const int  kk    = (t <= 128) ? t : 256 - t;
  const bool lower = (t <= 128);
  const float NRM = 1.0f / 65536.0f;
#pragma unroll
  for (int p = 0; p < 2; ++p) {
    float ar = t0r[kk * 5 + 2 * p],     ai = t0i[kk * 5 + 2 * p];
    float br = t0r[kk * 5 + 2 * p + 1], bi = t0i[kk * 5 + 2 * p + 1];
    sAr[t] = lower ? (ar - bi) : (ar + bi);   // Z = H(x0) + i*H(x1)
    sAi[t] = lower ? (ai + br) : (br - ai);
    fft256<true>(sAr, sAi, sBr, sBi, twr, twi, t);
    out[((((size_t)r * 8 + b) * 256) + x0 + 2 * p) * 256 + t]     = sAr[t] * NRM;
    out[((((size_t)r * 8 + b) * 256) + x0 + 2 * p + 1) * 256 + t] = sAi[t] * NRM;
  }
}

// ---------------------------------------------------------------------------
extern "C" void kernel_launch(void* const* d_in, const int* in_sizes, int n_in,
                              void* d_out, int out_size, void* d_ws, size_t ws_size,
                              hipStream_t stream)
{
  const float* vort = (const float*)d_in[0];
  float* out = (float*)d_out;

  // workspace carve-up (float2 units); total = 2,553,856 float2 = ~19.5 MiB
  float2* base = (float2*)d_ws;
  float2* u    = base;                 // 8*129*256   = 264192
  float2* h    = u + 264192;           // 264192
  float2* G    = h + 264192;           // 4*8*129*256 = 1056768
  float2* NL1  = G + 1056768;          // 8*86*256    = 176128
  float2* rec  = NL1 + 176128;         // 3*8*129*256 = 792576
  float2* W1   = G;                    // alias: only used before first G write

  static const double AL[6] = {0.0, 0.1496590219993, 0.3704009573644,
                               0.6222557631345, 0.9582821306748, 1.0};
  static const double BE[5] = {0.0, -0.4178904745, -1.192151694643,
                               -1.697784692471, -1.514183444257};
  static const double GA[5] = {0.1496590219993, 0.3792103129999, 0.8229550293869,
                               0.6994504559488, 0.1530572479681};
  const double DT = 0.001;

  hipLaunchKernelGGL(k_init_rows, dim3(256, 8), dim3(256), 0, stream, vort, W1);
  hipLaunchKernelGGL(k_init_cols, dim3(129, 8), dim3(256), 0, stream, W1, u);
  // prepare G from initial u (no update)
  hipLaunchKernelGGL(k_spectral, dim3(129, 8), dim3(256), 0, stream,
                     NL1, u, h, G, rec, 0.0f, 0.0f, 0.0f, 0, -1);

  for (int step = 1; step <= 90; ++step) {
    for (int k = 0; k < 5; ++k) {
      hipLaunchKernelGGL(k_real, dim3(64, 8), dim3(256), 0, stream, G, NL1);
      int recIdx = (k == 4 && step % 30 == 0) ? (step / 30 - 1) : -1;
      hipLaunchKernelGGL(k_spectral, dim3(129, 8), dim3(256), 0, stream,
                         NL1, u, h, G, rec,
                         (float)BE[k], (float)(GA[k] * DT),
                         (float)(0.5 * DT * (AL[k + 1] - AL[k])),
                         1, recIdx);
    }
  }

  hipLaunchKernelGGL(k_final_col, dim3(129, 8, 3), dim3(256), 0, stream, rec, G);
  hipLaunchKernelGGL(k_final_row, dim3(64, 8, 3), dim3(256), 0, stream, G, out);
}